// Round 7
// baseline (196.714 us; speedup 1.0000x reference)
//
#include <hip/hip_runtime.h>
#include <math.h>

#define E 4
#define TPB 256
#define RPB 8
#define NWAVES (TPB / 64)
#define SINKHORN_ITERS 20
#define SINKHORN_EPS 1e-6f

typedef float f4 __attribute__((ext_vector_type(4)));

// ws layout: [0, E*D)        ws_pre    = softmax(H_pre)            (E x D)
//            [E*D, 2*E*D)    ws_post2  = H_res @ softmax(H_post)   (E x D)
//            [2*E*D, +32)    ws_small: hres[16], mx[8], sm[8]

// ---------------------------------------------------------------------------
// prep_stats: 9 blocks, all latency paths parallel (measured-good R6).
//  blocks 0-7: softmax stats (max, sumexp) for (mat,row) pair p = blockIdx
//  block 8   : sinkhorn on wave 0 (lanes 0-15, shfl butterflies)
// ---------------------------------------------------------------------------
__global__ __launch_bounds__(TPB) void prep_stats(
    const float* __restrict__ Hres_l,
    const float* __restrict__ Hpre_l,
    const float* __restrict__ Hpost_l,
    float* __restrict__ ws_small,
    int D4)
{
    const int t = threadIdx.x;
    const int wave = t >> 6;
    const int lane = t & 63;

    if (blockIdx.x == 8) {
        if (wave == 0) {
            float a = (lane < E * E) ? Hres_l[lane] : -1e30f;
            float m = a;
#pragma unroll
            for (int off = 1; off < 16; off <<= 1)
                m = fmaxf(m, __shfl_xor(m, off, 16));
            a = expf(a - m);
            for (int it = 0; it < SINKHORN_ITERS; ++it) {
                float rs = a;                   // row sum (lanes sharing r)
                rs += __shfl_xor(rs, 1, 4);
                rs += __shfl_xor(rs, 2, 4);
                a /= (rs + SINKHORN_EPS);
                float cs = a;                   // col sum (lanes sharing c)
                cs += __shfl_xor(cs, 4, 16);
                cs += __shfl_xor(cs, 8, 16);
                a /= (cs + SINKHORN_EPS);
            }
            if (lane < E * E) ws_small[lane] = a;
        }
        return;
    }

    __shared__ float redm[NWAVES], reds[NWAVES];
    const int p = blockIdx.x;                   // 0..7: mat=p>>2, e=p&3
    const int mat = p >> 2, e = p & 3;
    const f4* rowp = (const f4*)((mat ? Hpost_l : Hpre_l) + (size_t)e * D4 * 4);

    // pass 1: row max
    float m = -1e30f;
    for (int i = t; i < D4; i += TPB) {
        f4 v = rowp[i];
        m = fmaxf(fmaxf(fmaxf(m, v.x), v.y), fmaxf(v.z, v.w));
    }
#pragma unroll
    for (int off = 1; off < 64; off <<= 1)
        m = fmaxf(m, __shfl_xor(m, off, 64));
    if (lane == 0) redm[wave] = m;
    __syncthreads();
    m = fmaxf(fmaxf(redm[0], redm[1]), fmaxf(redm[2], redm[3]));

    // pass 2: sum of exp (L2-hot)
    float s = 0.f;
    for (int i = t; i < D4; i += TPB) {
        f4 v = rowp[i];
        s += expf(v.x - m) + expf(v.y - m) + expf(v.z - m) + expf(v.w - m);
    }
#pragma unroll
    for (int off = 1; off < 64; off <<= 1)
        s += __shfl_xor(s, off, 64);
    if (lane == 0) reds[wave] = s;
    __syncthreads();
    if (t == 0) {
        ws_small[16 + p] = m;
        ws_small[24 + p] = reds[0] + reds[1] + reds[2] + reds[3];
    }
}

// ---------------------------------------------------------------------------
// prep_write: D4/TPB blocks (=4), one f4 column per thread (measured-good R6).
// ws_pre = softmax(H_pre); ws_post2 = H_res @ softmax(H_post).
// ---------------------------------------------------------------------------
__global__ __launch_bounds__(TPB) void prep_write(
    const float* __restrict__ Hpre_l,
    const float* __restrict__ Hpost_l,
    const float* __restrict__ ws_small,
    f4* __restrict__ wpre4,
    f4* __restrict__ wpost4,
    int D4)
{
    const int i = blockIdx.x * TPB + threadIdx.x;
    if (i >= D4) return;

    float hres[E * E];
#pragma unroll
    for (int k = 0; k < E * E; ++k) hres[k] = ws_small[k];
    float mpre[E], spre[E], mpost[E], spost[E];
#pragma unroll
    for (int e = 0; e < E; ++e) {
        mpre[e]  = ws_small[16 + e];     spre[e]  = 1.f / ws_small[24 + e];
        mpost[e] = ws_small[16 + E + e]; spost[e] = 1.f / ws_small[24 + E + e];
    }

    const f4* pre_l4  = (const f4*)Hpre_l;
    const f4* post_l4 = (const f4*)Hpost_l;
    f4 postv[E];
#pragma unroll
    for (int e = 0; e < E; ++e) {
        f4 v = pre_l4[(size_t)e * D4 + i];
        f4 o;
        o.x = expf(v.x - mpre[e]) * spre[e];
        o.y = expf(v.y - mpre[e]) * spre[e];
        o.z = expf(v.z - mpre[e]) * spre[e];
        o.w = expf(v.w - mpre[e]) * spre[e];
        wpre4[(size_t)e * D4 + i] = o;
        f4 w = post_l4[(size_t)e * D4 + i];
        postv[e].x = expf(w.x - mpost[e]) * spost[e];
        postv[e].y = expf(w.y - mpost[e]) * spost[e];
        postv[e].z = expf(w.z - mpost[e]) * spost[e];
        postv[e].w = expf(w.w - mpost[e]) * spost[e];
    }
#pragma unroll
    for (int ep = 0; ep < E; ++ep) {
        f4 o = hres[ep * E + 0] * postv[0] + hres[ep * E + 1] * postv[1] +
               hres[ep * E + 2] * postv[2] + hres[ep * E + 3] * postv[3];
        wpost4[(size_t)ep * D4 + i] = o;
    }
}

// ---------------------------------------------------------------------------
// mhc_fused: 8 rows per block, ONE kernel for both phases.
//  Phase 1: partial dots (runtime chunk loop — keeps VGPR in budget),
//           value-halving butterfly (31 shfl), cross-wave combine in LDS.
//  Phase 2: out[row][d] = sum_e xp[row][e] * ws_post2[e][d], NT stores.
// xp handoff stays in LDS (no global round-trip). __launch_bounds__(256,4)
// caps VGPR at 128 -> >=4 blocks/CU (16 waves/CU) for latency hiding.
// ---------------------------------------------------------------------------
__global__ __launch_bounds__(TPB, 4) void mhc_fused(
    const f4* __restrict__ x4,
    const f4* __restrict__ pre4,
    const f4* __restrict__ post4,
    f4* __restrict__ out4,
    int D4, int chunks)
{
    __shared__ float wred[NWAVES][RPB * E];
    __shared__ float sxp[RPB * E];
    const int t = threadIdx.x;
    const int wave = t >> 6;
    const int lane = t & 63;
    const long row0 = (long)blockIdx.x * RPB;

    float val[RPB * E];                  // packed partials, idx = r*E+e
#pragma unroll
    for (int i = 0; i < RPB * E; ++i) val[i] = 0.f;

    for (int k = 0; k < chunks; ++k) {
        const int d4 = k * TPB + t;
        f4 hp[E];
#pragma unroll
        for (int e = 0; e < E; ++e) hp[e] = pre4[(size_t)e * D4 + d4];
#pragma unroll
        for (int r = 0; r < RPB; ++r) {
            f4 xv = __builtin_nontemporal_load(&x4[(row0 + r) * D4 + d4]);
#pragma unroll
            for (int e = 0; e < E; ++e)
                val[r * E + e] += xv.x * hp[e].x + xv.y * hp[e].y +
                                  xv.z * hp[e].z + xv.w * hp[e].w;
        }
    }

    // value-halving butterfly: 32 -> 16 -> 8 -> 4 -> 2 -> 1 values/thread
    {
        const bool h0 = lane & 1;
        float a16[16];
#pragma unroll
        for (int i = 0; i < 16; ++i) {
            float send = h0 ? val[2 * i] : val[2 * i + 1];
            float recv = __shfl_xor(send, 1, 64);
            a16[i] = (h0 ? val[2 * i + 1] : val[2 * i]) + recv;
        }
        const bool h1 = (lane >> 1) & 1;
        float a8[8];
#pragma unroll
        for (int i = 0; i < 8; ++i) {
            float send = h1 ? a16[2 * i] : a16[2 * i + 1];
            float recv = __shfl_xor(send, 2, 64);
            a8[i] = (h1 ? a16[2 * i + 1] : a16[2 * i]) + recv;
        }
        const bool h2 = (lane >> 2) & 1;
        float a4[4];
#pragma unroll
        for (int i = 0; i < 4; ++i) {
            float send = h2 ? a8[2 * i] : a8[2 * i + 1];
            float recv = __shfl_xor(send, 4, 64);
            a4[i] = (h2 ? a8[2 * i + 1] : a8[2 * i]) + recv;
        }
        const bool h3 = (lane >> 3) & 1;
        float a2[2];
#pragma unroll
        for (int i = 0; i < 2; ++i) {
            float send = h3 ? a4[2 * i] : a4[2 * i + 1];
            float recv = __shfl_xor(send, 8, 64);
            a2[i] = (h3 ? a4[2 * i + 1] : a4[2 * i]) + recv;
        }
        const bool h4 = (lane >> 4) & 1;
        float send = h4 ? a2[0] : a2[1];
        float recv = __shfl_xor(send, 16, 64);
        float a1 = (h4 ? a2[1] : a2[0]) + recv;
        a1 += __shfl_xor(a1, 32, 64);    // cross 32-lane halves
        if (lane < 32) wred[wave][lane] = a1;   // v = lane & 31
    }
    __syncthreads();

    if (t < RPB * E)                     // t = v = r*E + e
        sxp[t] = wred[0][t] + wred[1][t] + wred[2][t] + wred[3][t];
    __syncthreads();

    float xp[RPB][E];
#pragma unroll
    for (int r = 0; r < RPB; ++r)
#pragma unroll
        for (int e = 0; e < E; ++e) xp[r][e] = sxp[r * E + e];

    for (int k = 0; k < chunks; ++k) {
        const int d4 = k * TPB + t;
        f4 hq[E];
#pragma unroll
        for (int e = 0; e < E; ++e) hq[e] = post4[(size_t)e * D4 + d4];
#pragma unroll
        for (int r = 0; r < RPB; ++r) {
            f4 o = xp[r][0] * hq[0] + xp[r][1] * hq[1] +
                   xp[r][2] * hq[2] + xp[r][3] * hq[3];
            __builtin_nontemporal_store(o, &out4[(row0 + r) * D4 + d4]);
        }
    }
}

extern "C" void kernel_launch(void* const* d_in, const int* in_sizes, int n_in,
                              void* d_out, int out_size, void* d_ws, size_t ws_size,
                              hipStream_t stream) {
    const float* x     = (const float*)d_in[0];
    const float* Hres  = (const float*)d_in[1];
    const float* Hpre  = (const float*)d_in[2];
    const float* Hpost = (const float*)d_in[3];
    float* out = (float*)d_out;

    const int D = in_sizes[2] / E;                  // 4096
    const long rows = (long)in_sizes[0] / D;        // B*S = 16384
    const int D4 = D / 4;
    const int chunks = D4 / TPB;                    // 4 for D=4096

    float* ws_pre   = (float*)d_ws;                 // E*D floats
    float* ws_post2 = ws_pre + (size_t)E * D;       // E*D floats
    float* ws_small = ws_post2 + (size_t)E * D;     // 32 floats

    prep_stats<<<9, TPB, 0, stream>>>(Hres, Hpre, Hpost, ws_small, D4);
    prep_write<<<(D4 + TPB - 1) / TPB, TPB, 0, stream>>>(
        Hpre, Hpost, ws_small, (f4*)ws_pre, (f4*)ws_post2, D4);

    const int grid = (int)(rows / RPB);             // 2048
    mhc_fused<<<grid, TPB, 0, stream>>>((const f4*)x, (const f4*)ws_pre,
                                        (const f4*)ws_post2, (f4*)out,
                                        D4, chunks);
}

// Round 10
// 127.239 us; speedup vs baseline: 1.5460x; 1.5460x over previous
//
#include <hip/hip_runtime.h>
#include <math.h>

#define E 4
#define TPB 256
#define RPB 8
#define NWAVES (TPB / 64)
#define SINKHORN_ITERS 20
#define SINKHORN_EPS 1e-6f

typedef float f4 __attribute__((ext_vector_type(4)));

// Two-kernel design, zero prep kernels:
//  xpre_osm: per-block on-the-fly softmax of H_pre (max pass over L2-hot
//            logits, then fused numerator/denominator accumulate while
//            streaming x), x_pre -> ws_xpre.
//  out_osm : per-block redundant sinkhorn (wave 0) + on-the-fly softmax of
//            H_post (max pass + denom pass over L2-hot logits), fold H_res
//            and 1/den into xp2, pure NT write stream of out.

// ---------------------------------------------------------------------------
// xpre_osm: x_pre[row][e] = sum_d x[row][d]*exp(pre[e][d]-mx[e]) / den[e]
// ---------------------------------------------------------------------------
__global__ __launch_bounds__(TPB) void xpre_osm(
    const f4* __restrict__ x4,
    const f4* __restrict__ preL4,       // raw H_pre logits, E x D4
    float* __restrict__ xpre,
    int D4, int chunks)
{
    __shared__ float redm[NWAVES][E];
    __shared__ float sden[NWAVES][E];
    __shared__ float wred[NWAVES][RPB * E];
    const int t = threadIdx.x;
    const int wave = t >> 6;
    const int lane = t & 63;
    const long row0 = (long)blockIdx.x * RPB;

    // pass A: row max of pre logits (L2-hot after first blocks)
    float mx[E];
#pragma unroll
    for (int e = 0; e < E; ++e) mx[e] = -1e30f;
    for (int k = 0; k < chunks; ++k) {
        const int i = k * TPB + t;
#pragma unroll
        for (int e = 0; e < E; ++e) {
            f4 v = preL4[(size_t)e * D4 + i];
            mx[e] = fmaxf(mx[e], fmaxf(fmaxf(v.x, v.y), fmaxf(v.z, v.w)));
        }
    }
#pragma unroll
    for (int e = 0; e < E; ++e) {
        float m = mx[e];
#pragma unroll
        for (int off = 1; off < 64; off <<= 1)
            m = fmaxf(m, __shfl_xor(m, off, 64));
        if (lane == 0) redm[wave][e] = m;
    }
    __syncthreads();
#pragma unroll
    for (int e = 0; e < E; ++e)
        mx[e] = fmaxf(fmaxf(redm[0][e], redm[1][e]),
                      fmaxf(redm[2][e], redm[3][e]));

    // main: stream x (NT), accumulate num[r][e] and den[e]
    float num[RPB * E];
#pragma unroll
    for (int i = 0; i < RPB * E; ++i) num[i] = 0.f;
    float den[E] = {0.f, 0.f, 0.f, 0.f};

    for (int k = 0; k < chunks; ++k) {
        const int i = k * TPB + t;
        f4 hp[E];
#pragma unroll
        for (int e = 0; e < E; ++e) {
            f4 v = preL4[(size_t)e * D4 + i];
            hp[e].x = expf(v.x - mx[e]);
            hp[e].y = expf(v.y - mx[e]);
            hp[e].z = expf(v.z - mx[e]);
            hp[e].w = expf(v.w - mx[e]);
            den[e] += hp[e].x + hp[e].y + hp[e].z + hp[e].w;
        }
#pragma unroll
        for (int r = 0; r < RPB; ++r) {
            f4 xv = __builtin_nontemporal_load(&x4[(row0 + r) * D4 + i]);
#pragma unroll
            for (int e = 0; e < E; ++e)
                num[r * E + e] += xv.x * hp[e].x + xv.y * hp[e].y +
                                  xv.z * hp[e].z + xv.w * hp[e].w;
        }
    }

    // reduce den: classic butterfly per e
#pragma unroll
    for (int e = 0; e < E; ++e) {
        float v = den[e];
#pragma unroll
        for (int off = 1; off < 64; off <<= 1) v += __shfl_xor(v, off, 64);
        if (lane == 0) sden[wave][e] = v;
    }

    // reduce num: value-halving butterfly (31 shfl), final value v = lane&31
    {
        const bool h0 = lane & 1;
        float a16[16];
#pragma unroll
        for (int i = 0; i < 16; ++i) {
            float send = h0 ? num[2 * i] : num[2 * i + 1];
            float recv = __shfl_xor(send, 1, 64);
            a16[i] = (h0 ? num[2 * i + 1] : num[2 * i]) + recv;
        }
        const bool h1 = (lane >> 1) & 1;
        float a8[8];
#pragma unroll
        for (int i = 0; i < 8; ++i) {
            float send = h1 ? a16[2 * i] : a16[2 * i + 1];
            float recv = __shfl_xor(send, 2, 64);
            a8[i] = (h1 ? a16[2 * i + 1] : a16[2 * i]) + recv;
        }
        const bool h2 = (lane >> 2) & 1;
        float a4[4];
#pragma unroll
        for (int i = 0; i < 4; ++i) {
            float send = h2 ? a8[2 * i] : a8[2 * i + 1];
            float recv = __shfl_xor(send, 4, 64);
            a4[i] = (h2 ? a8[2 * i + 1] : a8[2 * i]) + recv;
        }
        const bool h3 = (lane >> 3) & 1;
        float a2[2];
#pragma unroll
        for (int i = 0; i < 2; ++i) {
            float send = h3 ? a4[2 * i] : a4[2 * i + 1];
            float recv = __shfl_xor(send, 8, 64);
            a2[i] = (h3 ? a4[2 * i + 1] : a4[2 * i]) + recv;
        }
        const bool h4 = (lane >> 4) & 1;
        float send = h4 ? a2[0] : a2[1];
        float recv = __shfl_xor(send, 16, 64);
        float a1 = (h4 ? a2[1] : a2[0]) + recv;
        a1 += __shfl_xor(a1, 32, 64);
        if (lane < 32) wred[wave][lane] = a1;
    }
    __syncthreads();

    if (t < RPB * E) {                   // t = r*E + e
        const int e = t & 3;
        float numtot = wred[0][t] + wred[1][t] + wred[2][t] + wred[3][t];
        float dentot = sden[0][e] + sden[1][e] + sden[2][e] + sden[3][e];
        const int r = t >> 2;
        xpre[(row0 + r) * E + e] = numtot / dentot;
    }
}

// ---------------------------------------------------------------------------
// out_osm: out[row][d] = sum_e xp2[row][e] * exp(post[e][d]-mx[e])
//   where xp2[row][e] = (sum_ep xp[row][ep]*Hres[ep][e]) / den[e],
//   Hres = sinkhorn(H_res_logits) computed redundantly per block (wave 0).
// ---------------------------------------------------------------------------
__global__ __launch_bounds__(TPB) void out_osm(
    const float* __restrict__ xpre,
    const f4* __restrict__ postL4,      // raw H_post logits, E x D4
    const float* __restrict__ HresL,
    f4* __restrict__ out4,
    int D4, int chunks)
{
    __shared__ float sHres[E * E];
    __shared__ float sxp[RPB * E];
    __shared__ float redm[NWAVES][E];
    __shared__ float sden[NWAVES][E];
    const int t = threadIdx.x;
    const int wave = t >> 6;
    const int lane = t & 63;
    const long row0 = (long)blockIdx.x * RPB;

    // wave 0: sinkhorn (redundant per block, pure shfl chain)
    if (wave == 0) {
        float a = (lane < E * E) ? HresL[lane] : -1e30f;
        float m = a;
#pragma unroll
        for (int off = 1; off < 16; off <<= 1)
            m = fmaxf(m, __shfl_xor(m, off, 16));
        a = expf(a - m);
        for (int it = 0; it < SINKHORN_ITERS; ++it) {
            float rs = a;                       // row sum (lanes sharing r)
            rs += __shfl_xor(rs, 1, 4);
            rs += __shfl_xor(rs, 2, 4);
            a /= (rs + SINKHORN_EPS);
            float cs = a;                       // col sum (lanes sharing c)
            cs += __shfl_xor(cs, 4, 16);
            cs += __shfl_xor(cs, 8, 16);
            a /= (cs + SINKHORN_EPS);
        }
        if (lane < E * E) sHres[lane] = a;
    }
    // load xp for this block's rows
    if (t >= 64 && t < 64 + RPB * E) sxp[t - 64] = xpre[row0 * E + (t - 64)];

    // pass A: row max of post logits
    float mx[E];
#pragma unroll
    for (int e = 0; e < E; ++e) mx[e] = -1e30f;
    for (int k = 0; k < chunks; ++k) {
        const int i = k * TPB + t;
#pragma unroll
        for (int e = 0; e < E; ++e) {
            f4 v = postL4[(size_t)e * D4 + i];
            mx[e] = fmaxf(mx[e], fmaxf(fmaxf(v.x, v.y), fmaxf(v.z, v.w)));
        }
    }
#pragma unroll
    for (int e = 0; e < E; ++e) {
        float m = mx[e];
#pragma unroll
        for (int off = 1; off < 64; off <<= 1)
            m = fmaxf(m, __shfl_xor(m, off, 64));
        if (lane == 0) redm[wave][e] = m;
    }
    __syncthreads();                     // sHres, sxp, redm all ready
#pragma unroll
    for (int e = 0; e < E; ++e)
        mx[e] = fmaxf(fmaxf(redm[0][e], redm[1][e]),
                      fmaxf(redm[2][e], redm[3][e]));

    // pass B: den[e] = sum exp(post - mx)   (L2-hot)
    float den[E] = {0.f, 0.f, 0.f, 0.f};
    for (int k = 0; k < chunks; ++k) {
        const int i = k * TPB + t;
#pragma unroll
        for (int e = 0; e < E; ++e) {
            f4 v = postL4[(size_t)e * D4 + i];
            den[e] += expf(v.x - mx[e]) + expf(v.y - mx[e]) +
                      expf(v.z - mx[e]) + expf(v.w - mx[e]);
        }
    }
#pragma unroll
    for (int e = 0; e < E; ++e) {
        float v = den[e];
#pragma unroll
        for (int off = 1; off < 64; off <<= 1) v += __shfl_xor(v, off, 64);
        if (lane == 0) sden[wave][e] = v;
    }
    __syncthreads();

    // xp2[r][e] = (sum_ep xp[r][ep]*Hres[ep][e]) / den[e]
    float xp2[RPB][E];
#pragma unroll
    for (int e = 0; e < E; ++e) {
        float d = sden[0][e] + sden[1][e] + sden[2][e] + sden[3][e];
        float inv = 1.f / d;
#pragma unroll
        for (int r = 0; r < RPB; ++r) {
            float acc = sxp[r * E + 0] * sHres[0 * E + e] +
                        sxp[r * E + 1] * sHres[1 * E + e] +
                        sxp[r * E + 2] * sHres[2 * E + e] +
                        sxp[r * E + 3] * sHres[3 * E + e];
            xp2[r][e] = acc * inv;
        }
    }

    // main write loop: out = sum_e xp2[r][e]*exp(post-mx), NT stores
    for (int k = 0; k < chunks; ++k) {
        const int i = k * TPB + t;
        f4 hv[E];
#pragma unroll
        for (int e = 0; e < E; ++e) {
            f4 v = postL4[(size_t)e * D4 + i];
            hv[e].x = expf(v.x - mx[e]);
            hv[e].y = expf(v.y - mx[e]);
            hv[e].z = expf(v.z - mx[e]);
            hv[e].w = expf(v.w - mx[e]);
        }
#pragma unroll
        for (int r = 0; r < RPB; ++r) {
            f4 o = xp2[r][0] * hv[0] + xp2[r][1] * hv[1] +
                   xp2[r][2] * hv[2] + xp2[r][3] * hv[3];
            __builtin_nontemporal_store(o, &out4[(row0 + r) * D4 + i]);
        }
    }
}

extern "C" void kernel_launch(void* const* d_in, const int* in_sizes, int n_in,
                              void* d_out, int out_size, void* d_ws, size_t ws_size,
                              hipStream_t stream) {
    const float* x     = (const float*)d_in[0];
    const float* Hres  = (const float*)d_in[1];
    const float* Hpre  = (const float*)d_in[2];
    const float* Hpost = (const float*)d_in[3];
    float* out = (float*)d_out;

    const int D = in_sizes[2] / E;                  // 4096
    const long rows = (long)in_sizes[0] / D;        // B*S = 16384
    const int D4 = D / 4;
    const int chunks = D4 / TPB;                    // 4 for D=4096

    float* ws_xpre = (float*)d_ws;                  // rows*E floats

    const int grid = (int)(rows / RPB);             // 2048
    xpre_osm<<<grid, TPB, 0, stream>>>((const f4*)x, (const f4*)Hpre,
                                       ws_xpre, D4, chunks);
    out_osm<<<grid, TPB, 0, stream>>>(ws_xpre, (const f4*)Hpost, Hres,
                                      (f4*)out, D4, chunks);
}

// Round 11
// 114.596 us; speedup vs baseline: 1.7166x; 1.1103x over previous
//
#include <hip/hip_runtime.h>
#include <math.h>

#define E 4
#define TPB 256
#define RPB 8
#define NWAVES (TPB / 64)
#define SINKHORN_ITERS 20
#define SINKHORN_EPS 1e-6f

typedef float f4 __attribute__((ext_vector_type(4)));

// ws layout: [0, E*D)       ws_pre     = softmax(H_pre)    (E x D)
//            [E*D, 2*E*D)   ws_post_sm = softmax(H_post)   (E x D)
//            [2*E*D, ...)   ws_xpre    = x @ ws_pre^T      (rows x E)
//
// Structure (R6-derived, one fewer kernel/boundary):
//  prep    : 8 independent blocks; block p = (mat,row) pair: stats + write
//            that row's softmax. No cross-block deps, no second prep kernel.
//  xpre    : byte-identical to measured-good R6 xpre_kernel.
//  out     : R6 out_kernel + cheap prologue (wave-0 redundant sinkhorn +
//            fold H_res into xp2 via tiny LDS matmul).

// ---------------------------------------------------------------------------
// prep: block p (0..7): mat=p>>2, e=p&3. Row softmax start-to-finish.
// ---------------------------------------------------------------------------
__global__ __launch_bounds__(TPB) void prep(
    const float* __restrict__ Hpre_l,
    const float* __restrict__ Hpost_l,
    f4* __restrict__ wpre4,
    f4* __restrict__ wpost4,
    int D4)
{
    __shared__ float redm[NWAVES], reds[NWAVES];
    const int t = threadIdx.x;
    const int wave = t >> 6;
    const int lane = t & 63;
    const int p = blockIdx.x;
    const int mat = p >> 2, e = p & 3;
    const f4* rowp = (const f4*)((mat ? Hpost_l : Hpre_l) + (size_t)e * D4 * 4);
    f4* dst = (mat ? wpost4 : wpre4) + (size_t)e * D4;

    // pass 1: row max
    float m = -1e30f;
    for (int i = t; i < D4; i += TPB) {
        f4 v = rowp[i];
        m = fmaxf(fmaxf(fmaxf(m, v.x), v.y), fmaxf(v.z, v.w));
    }
#pragma unroll
    for (int off = 1; off < 64; off <<= 1)
        m = fmaxf(m, __shfl_xor(m, off, 64));
    if (lane == 0) redm[wave] = m;
    __syncthreads();
    m = fmaxf(fmaxf(redm[0], redm[1]), fmaxf(redm[2], redm[3]));

    // pass 2: sum of exp (L2-hot)
    float s = 0.f;
    for (int i = t; i < D4; i += TPB) {
        f4 v = rowp[i];
        s += expf(v.x - m) + expf(v.y - m) + expf(v.z - m) + expf(v.w - m);
    }
#pragma unroll
    for (int off = 1; off < 64; off <<= 1)
        s += __shfl_xor(s, off, 64);
    if (lane == 0) reds[wave] = s;
    __syncthreads();
    const float inv = 1.f / (reds[0] + reds[1] + reds[2] + reds[3]);

    // pass 3: write softmax row (L2-hot read)
    for (int i = t; i < D4; i += TPB) {
        f4 v = rowp[i];
        f4 o;
        o.x = expf(v.x - m) * inv;
        o.y = expf(v.y - m) * inv;
        o.z = expf(v.z - m) * inv;
        o.w = expf(v.w - m) * inv;
        dst[i] = o;
    }
}

// ---------------------------------------------------------------------------
// xpre_kernel: byte-identical to measured-good R6. Pure NT read stream of x;
// value-halving butterfly reduction (31 shfl).
// ---------------------------------------------------------------------------
__global__ __launch_bounds__(TPB) void xpre_kernel(
    const f4* __restrict__ x4,
    const f4* __restrict__ pre4,
    float* __restrict__ xpre,
    int D4, int chunks)
{
    __shared__ float wred[NWAVES][RPB * E];
    const int t = threadIdx.x;
    const int wave = t >> 6;
    const int lane = t & 63;
    const long row0 = (long)blockIdx.x * RPB;

    float val[RPB * E];                  // packed partials, idx = r*E+e
#pragma unroll
    for (int i = 0; i < RPB * E; ++i) val[i] = 0.f;

    for (int k = 0; k < chunks; ++k) {
        const int d4 = k * TPB + t;
        f4 hp[E];
#pragma unroll
        for (int e = 0; e < E; ++e) hp[e] = pre4[(size_t)e * D4 + d4];
#pragma unroll
        for (int r = 0; r < RPB; ++r) {
            f4 xv = __builtin_nontemporal_load(&x4[(row0 + r) * D4 + d4]);
#pragma unroll
            for (int e = 0; e < E; ++e)
                val[r * E + e] += xv.x * hp[e].x + xv.y * hp[e].y +
                                  xv.z * hp[e].z + xv.w * hp[e].w;
        }
    }

    // value-halving butterfly: 32 -> 16 -> 8 -> 4 -> 2 -> 1 values/thread
    {
        const bool h0 = lane & 1;
        float a16[16];
#pragma unroll
        for (int i = 0; i < 16; ++i) {
            float send = h0 ? val[2 * i] : val[2 * i + 1];
            float recv = __shfl_xor(send, 1, 64);
            a16[i] = (h0 ? val[2 * i + 1] : val[2 * i]) + recv;
        }
        const bool h1 = (lane >> 1) & 1;
        float a8[8];
#pragma unroll
        for (int i = 0; i < 8; ++i) {
            float send = h1 ? a16[2 * i] : a16[2 * i + 1];
            float recv = __shfl_xor(send, 2, 64);
            a8[i] = (h1 ? a16[2 * i + 1] : a16[2 * i]) + recv;
        }
        const bool h2 = (lane >> 2) & 1;
        float a4[4];
#pragma unroll
        for (int i = 0; i < 4; ++i) {
            float send = h2 ? a8[2 * i] : a8[2 * i + 1];
            float recv = __shfl_xor(send, 4, 64);
            a4[i] = (h2 ? a8[2 * i + 1] : a8[2 * i]) + recv;
        }
        const bool h3 = (lane >> 3) & 1;
        float a2[2];
#pragma unroll
        for (int i = 0; i < 2; ++i) {
            float send = h3 ? a4[2 * i] : a4[2 * i + 1];
            float recv = __shfl_xor(send, 8, 64);
            a2[i] = (h3 ? a4[2 * i + 1] : a4[2 * i]) + recv;
        }
        const bool h4 = (lane >> 4) & 1;
        float send = h4 ? a2[0] : a2[1];
        float recv = __shfl_xor(send, 16, 64);
        float a1 = (h4 ? a2[1] : a2[0]) + recv;
        a1 += __shfl_xor(a1, 32, 64);    // cross 32-lane halves
        if (lane < 32) wred[wave][lane] = a1;   // v = lane & 31
    }
    __syncthreads();

    if (t < RPB * E) {                   // t = v = r*E + e
        float s = wred[0][t] + wred[1][t] + wred[2][t] + wred[3][t];
        const int r = t >> 2, e = t & 3;
        xpre[(row0 + r) * E + e] = s;
    }
}

// ---------------------------------------------------------------------------
// out_kernel: R6 write-stream + prologue: wave-0 redundant sinkhorn (R10-
// proven) and xp2[r][e] = sum_ep xp[r][ep]*Hres[ep][e]. Main loop reads
// ws_post_sm (plain softmax) and NT-streams out.
// ---------------------------------------------------------------------------
__global__ __launch_bounds__(TPB) void out_kernel(
    const float* __restrict__ xpre,
    const f4* __restrict__ post4,       // ws_post_sm
    const float* __restrict__ HresL,
    f4* __restrict__ out4,
    int D4, int chunks)
{
    __shared__ float sHres[E * E];
    __shared__ float sxp[RPB * E];
    const int t = threadIdx.x;
    const int wave = t >> 6;
    const int lane = t & 63;
    const long row0 = (long)blockIdx.x * RPB;

    // wave 0: sinkhorn (redundant per block, pure shfl chain, ~0.2us)
    if (wave == 0) {
        float a = (lane < E * E) ? HresL[lane] : -1e30f;
        float m = a;
#pragma unroll
        for (int off = 1; off < 16; off <<= 1)
            m = fmaxf(m, __shfl_xor(m, off, 16));
        a = expf(a - m);
        for (int it = 0; it < SINKHORN_ITERS; ++it) {
            float rs = a;                       // row sum (lanes sharing r)
            rs += __shfl_xor(rs, 1, 4);
            rs += __shfl_xor(rs, 2, 4);
            a /= (rs + SINKHORN_EPS);
            float cs = a;                       // col sum (lanes sharing c)
            cs += __shfl_xor(cs, 4, 16);
            cs += __shfl_xor(cs, 8, 16);
            a /= (cs + SINKHORN_EPS);
        }
        if (lane < E * E) sHres[lane] = a;
    }
    if (t >= 64 && t < 64 + RPB * E) sxp[t - 64] = xpre[row0 * E + (t - 64)];
    __syncthreads();

    // xp2[r][e] = sum_ep xp[r][ep] * Hres[ep][e]
    float xp2[RPB][E];
#pragma unroll
    for (int r = 0; r < RPB; ++r)
#pragma unroll
        for (int e = 0; e < E; ++e)
            xp2[r][e] = sxp[r * E + 0] * sHres[0 * E + e] +
                        sxp[r * E + 1] * sHres[1 * E + e] +
                        sxp[r * E + 2] * sHres[2 * E + e] +
                        sxp[r * E + 3] * sHres[3 * E + e];

    for (int k = 0; k < chunks; ++k) {
        const int d4 = k * TPB + t;
        f4 hq[E];
#pragma unroll
        for (int e = 0; e < E; ++e) hq[e] = post4[(size_t)e * D4 + d4];
#pragma unroll
        for (int r = 0; r < RPB; ++r) {
            f4 o = xp2[r][0] * hq[0] + xp2[r][1] * hq[1] +
                   xp2[r][2] * hq[2] + xp2[r][3] * hq[3];
            __builtin_nontemporal_store(o, &out4[(row0 + r) * D4 + d4]);
        }
    }
}

extern "C" void kernel_launch(void* const* d_in, const int* in_sizes, int n_in,
                              void* d_out, int out_size, void* d_ws, size_t ws_size,
                              hipStream_t stream) {
    const float* x     = (const float*)d_in[0];
    const float* Hres  = (const float*)d_in[1];
    const float* Hpre  = (const float*)d_in[2];
    const float* Hpost = (const float*)d_in[3];
    float* out = (float*)d_out;

    const int D = in_sizes[2] / E;                  // 4096
    const long rows = (long)in_sizes[0] / D;        // B*S = 16384
    const int D4 = D / 4;
    const int chunks = D4 / TPB;                    // 4 for D=4096

    float* ws_pre     = (float*)d_ws;               // E*D floats
    float* ws_post_sm = ws_pre + (size_t)E * D;     // E*D floats
    float* ws_xpre    = ws_post_sm + (size_t)E * D; // rows*E floats

    prep<<<2 * E, TPB, 0, stream>>>(Hpre, Hpost, (f4*)ws_pre,
                                    (f4*)ws_post_sm, D4);

    const int grid = (int)(rows / RPB);             // 2048
    xpre_kernel<<<grid, TPB, 0, stream>>>((const f4*)x, (const f4*)ws_pre,
                                          ws_xpre, D4, chunks);
    out_kernel<<<grid, TPB, 0, stream>>>(ws_xpre, (const f4*)ws_post_sm,
                                         Hres, (f4*)out, D4, chunks);
}

// Round 12
// 111.196 us; speedup vs baseline: 1.7691x; 1.0306x over previous
//
#include <hip/hip_runtime.h>
#include <math.h>

#define E 4
#define TPB 256
#define RPB 8
#define NWAVES (TPB / 64)
#define SINKHORN_ITERS 20
#define SINKHORN_EPS 1e-6f

typedef float f4 __attribute__((ext_vector_type(4)));

// Measured-best structure (R6, 110.8 us):
//  prep_stats (9 blocks)  -> prep_write (4 blocks) -> xpre (2048) -> out (2048)
// ws layout: [0, E*D)        ws_pre    = softmax(H_pre)            (E x D)
//            [E*D, 2*E*D)    ws_post2  = H_res @ softmax(H_post)   (E x D)
//            [2*E*D, +32)    ws_small: hres[16], mx[8], sm[8]
//            [2*E*D+32, ...) ws_xpre: rows*E floats

// ---------------------------------------------------------------------------
// prep_stats: 9 blocks, all latency paths parallel.
//  blocks 0-7: softmax stats (max, sumexp) for (mat,row) pair p = blockIdx
//  block 8   : sinkhorn on wave 0 (lanes 0-15, shfl butterflies)
// ---------------------------------------------------------------------------
__global__ __launch_bounds__(TPB) void prep_stats(
    const float* __restrict__ Hres_l,
    const float* __restrict__ Hpre_l,
    const float* __restrict__ Hpost_l,
    float* __restrict__ ws_small,
    int D4)
{
    const int t = threadIdx.x;
    const int wave = t >> 6;
    const int lane = t & 63;

    if (blockIdx.x == 8) {
        if (wave == 0) {
            float a = (lane < E * E) ? Hres_l[lane] : -1e30f;
            float m = a;
#pragma unroll
            for (int off = 1; off < 16; off <<= 1)
                m = fmaxf(m, __shfl_xor(m, off, 16));
            a = expf(a - m);
            for (int it = 0; it < SINKHORN_ITERS; ++it) {
                float rs = a;                   // row sum (lanes sharing r)
                rs += __shfl_xor(rs, 1, 4);
                rs += __shfl_xor(rs, 2, 4);
                a /= (rs + SINKHORN_EPS);
                float cs = a;                   // col sum (lanes sharing c)
                cs += __shfl_xor(cs, 4, 16);
                cs += __shfl_xor(cs, 8, 16);
                a /= (cs + SINKHORN_EPS);
            }
            if (lane < E * E) ws_small[lane] = a;
        }
        return;
    }

    __shared__ float redm[NWAVES], reds[NWAVES];
    const int p = blockIdx.x;                   // 0..7: mat=p>>2, e=p&3
    const int mat = p >> 2, e = p & 3;
    const f4* rowp = (const f4*)((mat ? Hpost_l : Hpre_l) + (size_t)e * D4 * 4);

    // pass 1: row max
    float m = -1e30f;
    for (int i = t; i < D4; i += TPB) {
        f4 v = rowp[i];
        m = fmaxf(fmaxf(fmaxf(m, v.x), v.y), fmaxf(v.z, v.w));
    }
#pragma unroll
    for (int off = 1; off < 64; off <<= 1)
        m = fmaxf(m, __shfl_xor(m, off, 64));
    if (lane == 0) redm[wave] = m;
    __syncthreads();
    m = fmaxf(fmaxf(redm[0], redm[1]), fmaxf(redm[2], redm[3]));

    // pass 2: sum of exp (L2-hot)
    float s = 0.f;
    for (int i = t; i < D4; i += TPB) {
        f4 v = rowp[i];
        s += expf(v.x - m) + expf(v.y - m) + expf(v.z - m) + expf(v.w - m);
    }
#pragma unroll
    for (int off = 1; off < 64; off <<= 1)
        s += __shfl_xor(s, off, 64);
    if (lane == 0) reds[wave] = s;
    __syncthreads();
    if (t == 0) {
        ws_small[16 + p] = m;
        ws_small[24 + p] = reds[0] + reds[1] + reds[2] + reds[3];
    }
}

// ---------------------------------------------------------------------------
// prep_write: D4/TPB blocks (=4), one f4 column per thread.
// ws_pre = softmax(H_pre); ws_post2 = H_res @ softmax(H_post).
// ---------------------------------------------------------------------------
__global__ __launch_bounds__(TPB) void prep_write(
    const float* __restrict__ Hpre_l,
    const float* __restrict__ Hpost_l,
    const float* __restrict__ ws_small,
    f4* __restrict__ wpre4,
    f4* __restrict__ wpost4,
    int D4)
{
    const int i = blockIdx.x * TPB + threadIdx.x;
    if (i >= D4) return;

    float hres[E * E];
#pragma unroll
    for (int k = 0; k < E * E; ++k) hres[k] = ws_small[k];
    float mpre[E], spre[E], mpost[E], spost[E];
#pragma unroll
    for (int e = 0; e < E; ++e) {
        mpre[e]  = ws_small[16 + e];     spre[e]  = 1.f / ws_small[24 + e];
        mpost[e] = ws_small[16 + E + e]; spost[e] = 1.f / ws_small[24 + E + e];
    }

    const f4* pre_l4  = (const f4*)Hpre_l;
    const f4* post_l4 = (const f4*)Hpost_l;
    f4 postv[E];
#pragma unroll
    for (int e = 0; e < E; ++e) {
        f4 v = pre_l4[(size_t)e * D4 + i];
        f4 o;
        o.x = expf(v.x - mpre[e]) * spre[e];
        o.y = expf(v.y - mpre[e]) * spre[e];
        o.z = expf(v.z - mpre[e]) * spre[e];
        o.w = expf(v.w - mpre[e]) * spre[e];
        wpre4[(size_t)e * D4 + i] = o;
        f4 w = post_l4[(size_t)e * D4 + i];
        postv[e].x = expf(w.x - mpost[e]) * spost[e];
        postv[e].y = expf(w.y - mpost[e]) * spost[e];
        postv[e].z = expf(w.z - mpost[e]) * spost[e];
        postv[e].w = expf(w.w - mpost[e]) * spost[e];
    }
#pragma unroll
    for (int ep = 0; ep < E; ++ep) {
        f4 o = hres[ep * E + 0] * postv[0] + hres[ep * E + 1] * postv[1] +
               hres[ep * E + 2] * postv[2] + hres[ep * E + 3] * postv[3];
        wpost4[(size_t)ep * D4 + i] = o;
    }
}

// ---------------------------------------------------------------------------
// xpre_kernel: x_pre[row][e] = dot(x[row], ws_pre[e]). Pure read stream of x
// (nontemporal). 8 rows per block. Reduction = value-halving butterfly
// (31 shfl instead of 192): step s keeps packed elements whose index-parity
// == lane-bit s; final value v = lane&31, then one xor-32 shfl.
// ---------------------------------------------------------------------------
__global__ __launch_bounds__(TPB) void xpre_kernel(
    const f4* __restrict__ x4,
    const f4* __restrict__ pre4,
    float* __restrict__ xpre,
    int D4, int chunks)
{
    __shared__ float wred[NWAVES][RPB * E];
    const int t = threadIdx.x;
    const int wave = t >> 6;
    const int lane = t & 63;
    const long row0 = (long)blockIdx.x * RPB;

    float val[RPB * E];                  // packed partials, idx = r*E+e
#pragma unroll
    for (int i = 0; i < RPB * E; ++i) val[i] = 0.f;

    for (int k = 0; k < chunks; ++k) {
        const int d4 = k * TPB + t;
        f4 hp[E];
#pragma unroll
        for (int e = 0; e < E; ++e) hp[e] = pre4[(size_t)e * D4 + d4];
#pragma unroll
        for (int r = 0; r < RPB; ++r) {
            f4 xv = __builtin_nontemporal_load(&x4[(row0 + r) * D4 + d4]);
#pragma unroll
            for (int e = 0; e < E; ++e)
                val[r * E + e] += xv.x * hp[e].x + xv.y * hp[e].y +
                                  xv.z * hp[e].z + xv.w * hp[e].w;
        }
    }

    // value-halving butterfly: 32 -> 16 -> 8 -> 4 -> 2 -> 1 values/thread
    {
        const bool h0 = lane & 1;
        float a16[16];
#pragma unroll
        for (int i = 0; i < 16; ++i) {
            float send = h0 ? val[2 * i] : val[2 * i + 1];
            float recv = __shfl_xor(send, 1, 64);
            a16[i] = (h0 ? val[2 * i + 1] : val[2 * i]) + recv;
        }
        const bool h1 = (lane >> 1) & 1;
        float a8[8];
#pragma unroll
        for (int i = 0; i < 8; ++i) {
            float send = h1 ? a16[2 * i] : a16[2 * i + 1];
            float recv = __shfl_xor(send, 2, 64);
            a8[i] = (h1 ? a16[2 * i + 1] : a16[2 * i]) + recv;
        }
        const bool h2 = (lane >> 2) & 1;
        float a4[4];
#pragma unroll
        for (int i = 0; i < 4; ++i) {
            float send = h2 ? a8[2 * i] : a8[2 * i + 1];
            float recv = __shfl_xor(send, 4, 64);
            a4[i] = (h2 ? a8[2 * i + 1] : a8[2 * i]) + recv;
        }
        const bool h3 = (lane >> 3) & 1;
        float a2[2];
#pragma unroll
        for (int i = 0; i < 2; ++i) {
            float send = h3 ? a4[2 * i] : a4[2 * i + 1];
            float recv = __shfl_xor(send, 8, 64);
            a2[i] = (h3 ? a4[2 * i + 1] : a4[2 * i]) + recv;
        }
        const bool h4 = (lane >> 4) & 1;
        float send = h4 ? a2[0] : a2[1];
        float recv = __shfl_xor(send, 16, 64);
        float a1 = (h4 ? a2[1] : a2[0]) + recv;
        a1 += __shfl_xor(a1, 32, 64);    // cross 32-lane halves
        if (lane < 32) wred[wave][lane] = a1;   // v = lane & 31
    }
    __syncthreads();

    if (t < RPB * E) {                   // t = v = r*E + e
        float s = wred[0][t] + wred[1][t] + wred[2][t] + wred[3][t];
        const int r = t >> 2, e = t & 3;
        xpre[(row0 + r) * E + e] = s;
    }
}

// ---------------------------------------------------------------------------
// out_kernel: out[row][d] = sum_e x_pre[row][e] * ws_post2[e][d].
// Pure write stream (nontemporal stores).
// ---------------------------------------------------------------------------
__global__ __launch_bounds__(TPB) void out_kernel(
    const float* __restrict__ xpre,
    const f4* __restrict__ post4,
    f4* __restrict__ out4,
    int D4, int chunks)
{
    __shared__ float sxp[RPB * E];
    const int t = threadIdx.x;
    const long row0 = (long)blockIdx.x * RPB;

    if (t < RPB * E) sxp[t] = xpre[row0 * E + t];
    __syncthreads();

    float xp[RPB][E];
#pragma unroll
    for (int r = 0; r < RPB; ++r)
#pragma unroll
        for (int e = 0; e < E; ++e) xp[r][e] = sxp[r * E + e];

    for (int k = 0; k < chunks; ++k) {
        const int d4 = k * TPB + t;
        f4 hq[E];
#pragma unroll
        for (int e = 0; e < E; ++e) hq[e] = post4[(size_t)e * D4 + d4];
#pragma unroll
        for (int r = 0; r < RPB; ++r) {
            f4 o = xp[r][0] * hq[0] + xp[r][1] * hq[1] +
                   xp[r][2] * hq[2] + xp[r][3] * hq[3];
            __builtin_nontemporal_store(o, &out4[(row0 + r) * D4 + d4]);
        }
    }
}

extern "C" void kernel_launch(void* const* d_in, const int* in_sizes, int n_in,
                              void* d_out, int out_size, void* d_ws, size_t ws_size,
                              hipStream_t stream) {
    const float* x     = (const float*)d_in[0];
    const float* Hres  = (const float*)d_in[1];
    const float* Hpre  = (const float*)d_in[2];
    const float* Hpost = (const float*)d_in[3];
    float* out = (float*)d_out;

    const int D = in_sizes[2] / E;                  // 4096
    const long rows = (long)in_sizes[0] / D;        // B*S = 16384
    const int D4 = D / 4;
    const int chunks = D4 / TPB;                    // 4 for D=4096

    float* ws_pre   = (float*)d_ws;                 // E*D floats
    float* ws_post2 = ws_pre + (size_t)E * D;       // E*D floats
    float* ws_small = ws_post2 + (size_t)E * D;     // 32 floats
    float* ws_xpre  = ws_small + 32;                // rows*E floats

    prep_stats<<<9, TPB, 0, stream>>>(Hres, Hpre, Hpost, ws_small, D4);
    prep_write<<<(D4 + TPB - 1) / TPB, TPB, 0, stream>>>(
        Hpre, Hpost, ws_small, (f4*)ws_pre, (f4*)ws_post2, D4);

    const int grid = (int)(rows / RPB);             // 2048
    xpre_kernel<<<grid, TPB, 0, stream>>>((const f4*)x, (const f4*)ws_pre,
                                          ws_xpre, D4, chunks);
    out_kernel<<<grid, TPB, 0, stream>>>(ws_xpre, (const f4*)ws_post2,
                                         (f4*)out, D4, chunks);
}